// Round 10
// baseline (186.497 us; speedup 1.0000x reference)
//
#include <hip/hip_runtime.h>
#include <hip/hip_bf16.h>

typedef unsigned short u16;
typedef unsigned u32;
typedef __attribute__((ext_vector_type(4))) unsigned short u16x4;
typedef __attribute__((ext_vector_type(8))) unsigned short u16x8;
typedef __attribute__((ext_vector_type(4))) unsigned u32x4;
typedef __attribute__((ext_vector_type(8))) __bf16 bf16x8;
typedef __attribute__((ext_vector_type(4))) float f32x4;

typedef __attribute__((address_space(1))) void as1v;
typedef __attribute__((address_space(3))) void as3v;

#define MFMA16(a, b, c) __builtin_amdgcn_mfma_f32_16x16x32_bf16(a, b, c, 0, 0, 0)

#if __has_builtin(__builtin_amdgcn_permlane16_swap) && __has_builtin(__builtin_amdgcn_permlane32_swap)
#define HAVE_PERMLANE_SWAP 1
#else
#define HAVE_PERMLANE_SWAP 0
#endif

__device__ __forceinline__ u16 f2bf(float f) {
    unsigned u = __builtin_bit_cast(unsigned, f);
    u += 0x7fffu + ((u >> 16) & 1u);
    return (u16)(u >> 16);
}

__device__ __forceinline__ u32 pkbf(float lo, float hi) {
    u32 r;
    asm("v_cvt_pk_bf16_f32 %0, %1, %2" : "=v"(r) : "v"(lo), "v"(hi));
    return r;
}

__device__ __forceinline__ void gload16(const void* g, void* l) {
    __builtin_amdgcn_global_load_lds((as1v*)g, (as3v*)l, 16, 0, 0);
}

// cross-lane reduce over lanes {l, l^16, l^32, l^48} — direction-proof.
__device__ __forceinline__ float redmax_cross(float v) {
#if HAVE_PERMLANE_SWAP
    u32 xu = __builtin_bit_cast(u32, v);
    auto r16 = __builtin_amdgcn_permlane16_swap(xu, xu, false, false);
    float a = fmaxf(__builtin_bit_cast(float, (u32)r16[0]),
                    __builtin_bit_cast(float, (u32)r16[1]));
    u32 au = __builtin_bit_cast(u32, a);
    auto r32 = __builtin_amdgcn_permlane32_swap(au, au, false, false);
    return fmaxf(__builtin_bit_cast(float, (u32)r32[0]),
                 __builtin_bit_cast(float, (u32)r32[1]));
#else
    v = fmaxf(v, __shfl_xor(v, 16, 64));
    return fmaxf(v, __shfl_xor(v, 32, 64));
#endif
}

__device__ __forceinline__ float redsum_cross(float v) {
#if HAVE_PERMLANE_SWAP
    u32 xu = __builtin_bit_cast(u32, v);
    auto r16 = __builtin_amdgcn_permlane16_swap(xu, xu, false, false);
    float a = __builtin_bit_cast(float, (u32)r16[0]) +
              __builtin_bit_cast(float, (u32)r16[1]);
    u32 au = __builtin_bit_cast(u32, a);
    auto r32 = __builtin_amdgcn_permlane32_swap(au, au, false, false);
    return __builtin_bit_cast(float, (u32)r32[0]) +
           __builtin_bit_cast(float, (u32)r32[1]);
#else
    v += __shfl_xor(v, 16, 64);
    return v + __shfl_xor(v, 32, 64);
#endif
}

// ---------------------------------------------------------------------------
__global__ void convert_f32_bf16(const float* __restrict__ in, u16* __restrict__ out, int n4) {
    int i = blockIdx.x * blockDim.x + threadIdx.x;
    if (i < n4) {
        float4 v = *(const float4*)&in[(size_t)i * 4];
        u16x4 o;
        o.x = f2bf(v.x); o.y = f2bf(v.y); o.z = f2bf(v.z); o.w = f2bf(v.w);
        *(u16x4*)&out[(size_t)i * 4] = o;
    }
}

// ---------------------------------------------------------------------------
__global__ void transpose_convert(const float* __restrict__ in, u16* __restrict__ out, int R, int C) {
    __shared__ float tl[64][65];
    const int rb = blockIdx.x, cb = blockIdx.y;
    const int tid = threadIdx.x;
    for (int it = 0; it < 4; ++it) {
        int lin = (tid + it * 256) * 4;
        int r = lin >> 6, c = lin & 63;
        float4 v = *(const float4*)&in[(size_t)(rb * 64 + r) * C + cb * 64 + c];
        tl[r][c + 0] = v.x; tl[r][c + 1] = v.y; tl[r][c + 2] = v.z; tl[r][c + 3] = v.w;
    }
    __syncthreads();
    for (int it = 0; it < 4; ++it) {
        int lin = (tid + it * 256) * 4;
        int oc = lin >> 6, orr = lin & 63;
        u16x4 o;
        o.x = f2bf(tl[orr + 0][oc]);
        o.y = f2bf(tl[orr + 1][oc]);
        o.z = f2bf(tl[orr + 2][oc]);
        o.w = f2bf(tl[orr + 3][oc]);
        *(u16x4*)&out[(size_t)(cb * 64 + oc) * R + rb * 64 + orr] = o;
    }
}

// ---------------------------------------------------------------------------
__global__ void transpose_v(const u16* __restrict__ vbuf, u16* __restrict__ vtb) {
    __shared__ u16 tl[64][65];
    const int nb = blockIdx.x, bh = blockIdx.y;
    const int tid = threadIdx.x;
    for (int it = 0; it < 2; ++it) {
        int lin = (tid + it * 256) * 8;
        int nl = lin >> 6, dh = lin & 63;
        u16x8 v = *(const u16x8*)&vbuf[((size_t)bh * 2048 + nb * 64 + nl) * 64 + dh];
#pragma unroll
        for (int j = 0; j < 8; ++j) tl[dh + j][nl] = v[j];
    }
    __syncthreads();
    for (int it = 0; it < 2; ++it) {
        int lin = (tid + it * 256) * 8;
        int dh = lin >> 6, nl = lin & 63;
        u16x8 o;
#pragma unroll
        for (int j = 0; j < 8; ++j) o[j] = tl[dh][nl + j];
        *(u16x8*)&vtb[((size_t)bh * 64 + dh) * 2048 + nb * 64 + nl] = o;
    }
}

// ---------------------------------------------------------------------------
// QKV projection GEMM, deep-pipelined 256x128 tile (r9-verified skeleton).
// M=8192, N=3072, K=1024. Grid 768 = 3 exact dispatch rounds at 1 block/CU.
// Epilogue: wave-private LDS staging (8KB, XOR-swizzled) -> coalesced
// global_store_dwordx4 into q/k/v [b,h][n][64] (each wave's 128x32 tile maps
// to one (b,h,dh-half) slice).
__global__ __launch_bounds__(512, 2) void gemm256_qkv(
    const u16* __restrict__ A, const u16* __restrict__ Bt, const float* __restrict__ bias,
    u16* __restrict__ qb, u16* __restrict__ kb, u16* __restrict__ vb) {
    constexpr int K = 1024;
    constexpr int NT = 32;
    __shared__ u16 ldsu[49152];   // 96 KB

    const int bid = blockIdx.x;
    const int swz = (bid & 7) * 96 + (bid >> 3);   // XCD-contiguous
    const int bm = swz / 24, bn = swz % 24;

    const int tid = threadIdx.x, wid = tid >> 6, lane = tid & 63;
    const int wr = wid >> 2, wc = wid & 3;
    const int l15 = lane & 15, lhi = lane >> 4;

    const int sslot = (lane & 7) ^ (lane >> 3);
    const int kcol = (sslot & 3) * 8;
    const int mloc = (lane >> 3) * 2 + (sslot >> 2);

    const u16* Arow[2];
#pragma unroll
    for (int li = 0; li < 2; ++li) {
        int sg = wid * 2 + li;
        Arow[li] = A + (size_t)(bm * 256 + sg * 16 + mloc) * K + kcol;
    }
    const u16* Brow = Bt + (size_t)(bn * 128 + wid * 16 + mloc) * K + kcol;

    auto stageA = [&](int buf, int t) {
#pragma unroll
        for (int li = 0; li < 2; ++li) {
            int sg = wid * 2 + li;
            gload16(Arow[li] + t * 32, (char*)ldsu + buf * 24576 + sg * 1024);
        }
    };
    auto stageB = [&](int buf, int t) {
        gload16(Brow + t * 32, (char*)ldsu + buf * 24576 + 16384 + wid * 1024);
    };

    const int rslot = ((l15 & 1) * 4 + lhi) ^ ((l15 >> 1) & 7);
    const int fragoff = (l15 >> 1) * 64 + rslot * 8;

    f32x4 acc[8][2];
#pragma unroll
    for (int i = 0; i < 8; ++i) {
        acc[i][0] = (f32x4){0.f, 0.f, 0.f, 0.f};
        acc[i][1] = (f32x4){0.f, 0.f, 0.f, 0.f};
    }

    auto doTile = [&](int cur, int tstage, bool dostage) {
        const u16* Ab = ldsu + cur * 12288 + wr * 4096 + fragoff;
        const u16* Bb = ldsu + cur * 12288 + 8192 + wc * 1024 + fragoff;
        bf16x8 af[8], b0, b1;
#pragma unroll
        for (int mf = 0; mf < 8; ++mf) af[mf] = *(const bf16x8*)(Ab + mf * 512);
        b0 = *(const bf16x8*)(Bb);
        b1 = *(const bf16x8*)(Bb + 512);
        if (dostage) stageA(tstage & 3, tstage);
        __builtin_amdgcn_s_setprio(1);
#pragma unroll
        for (int mf = 0; mf < 8; ++mf) acc[mf][0] = MFMA16(af[mf], b0, acc[mf][0]);
        __builtin_amdgcn_s_setprio(0);
        if (dostage) stageB(tstage & 3, tstage);
        __builtin_amdgcn_s_setprio(1);
#pragma unroll
        for (int mf = 0; mf < 8; ++mf) acc[mf][1] = MFMA16(af[mf], b1, acc[mf][1]);
        __builtin_amdgcn_s_setprio(0);
    };

    stageA(0, 0); stageB(0, 0);
    stageA(1, 1); stageB(1, 1);
    stageA(2, 2); stageB(2, 2);
    asm volatile("s_waitcnt vmcnt(6)" ::: "memory");
    __builtin_amdgcn_s_barrier();
    __builtin_amdgcn_sched_barrier(0);

    for (int t = 0; t < NT - 3; ++t) {
        doTile(t & 3, t + 3, true);
        asm volatile("s_waitcnt vmcnt(6)" ::: "memory");
        __builtin_amdgcn_s_barrier();
        __builtin_amdgcn_sched_barrier(0);
    }
    doTile((NT - 3) & 3, 0, false);
    asm volatile("s_waitcnt vmcnt(3)" ::: "memory");
    __builtin_amdgcn_s_barrier();
    __builtin_amdgcn_sched_barrier(0);
    doTile((NT - 2) & 3, 0, false);
    asm volatile("s_waitcnt vmcnt(0)" ::: "memory");
    __builtin_amdgcn_s_barrier();
    __builtin_amdgcn_sched_barrier(0);
    doTile((NT - 1) & 3, 0, false);

    // ---- epilogue: LDS-staged coalesced scatter into q/k/v ----
    __syncthreads();   // all pipeline LDS reads done before reuse
    const int cg0 = bn * 128 + wc * 32;        // wave's 32-col group (one head-half)
    const int which = cg0 >> 10, rem = cg0 & 1023;
    u16* dst = (which == 0) ? qb : (which == 1) ? kb : vb;
    const float qs = (which == 0) ? 0.18033688011112042f : 1.0f;  // 0.125*log2e
    const int hh = rem >> 6, dh0 = rem & 63;
    const int rgb0 = bm * 256 + wr * 128;
    const int bb = rgb0 >> 11, n0 = rgb0 & 2047;
    char* lep = (char*)ldsu + wid * 8192;
    float bv0 = bias[cg0 + l15], bv1 = bias[cg0 + 16 + l15];
#pragma unroll
    for (int mf = 0; mf < 8; ++mf)
#pragma unroll
        for (int v = 0; v < 4; ++v) {
            int row = mf * 16 + lhi * 4 + v;
            int sw = ((row >> 2) & 3) << 4;
            *(u16*)(lep + row * 64 + ((l15 * 2) ^ sw)) =
                f2bf((acc[mf][0][v] + bv0) * qs);
            *(u16*)(lep + row * 64 + ((32 + l15 * 2) ^ sw)) =
                f2bf((acc[mf][1][v] + bv1) * qs);
        }
    // wave-private read-back + coalesced 16B stores (1 KB contiguous / instr)
    const size_t gbase = (((size_t)bb * 16 + hh) * 2048 + n0) * 64 + dh0;
#pragma unroll
    for (int it = 0; it < 8; ++it) {
        int idx = it * 64 + lane;
        int row = idx >> 2, j = idx & 3;
        u16x8 vv = *(const u16x8*)(lep + row * 64 + ((j * 16) ^ (((row >> 2) & 3) << 4)));
        *(u16x8*)&dst[gbase + (size_t)row * 64 + j * 8] = vv;
    }
}

// ---------------------------------------------------------------------------
// Output projection GEMM, deep-pipelined 256x128 tile (verified r9).
__global__ __launch_bounds__(512, 2) void gemm256_out(
    const u16* __restrict__ A, const u16* __restrict__ Bt, const float* __restrict__ bias,
    float* __restrict__ outf) {
    constexpr int K = 1024;
    constexpr int NT = 32;
    __shared__ u16 ldsu[49152];   // 96 KB

    const int bid = blockIdx.x;
    const int swz = (bid & 7) * 32 + (bid >> 3);   // XCD-contiguous bm
    const int bm = swz >> 3, bn = swz & 7;

    const int tid = threadIdx.x, wid = tid >> 6, lane = tid & 63;
    const int wr = wid >> 2, wc = wid & 3;
    const int l15 = lane & 15, lhi = lane >> 4;

    const int sslot = (lane & 7) ^ (lane >> 3);
    const int kcol = (sslot & 3) * 8;
    const int mloc = (lane >> 3) * 2 + (sslot >> 2);

    const u16* Arow[2];
#pragma unroll
    for (int li = 0; li < 2; ++li) {
        int sg = wid * 2 + li;
        Arow[li] = A + (size_t)(bm * 256 + sg * 16 + mloc) * K + kcol;
    }
    const u16* Brow = Bt + (size_t)(bn * 128 + wid * 16 + mloc) * K + kcol;

    auto stageA = [&](int buf, int t) {
#pragma unroll
        for (int li = 0; li < 2; ++li) {
            int sg = wid * 2 + li;
            gload16(Arow[li] + t * 32, (char*)ldsu + buf * 24576 + sg * 1024);
        }
    };
    auto stageB = [&](int buf, int t) {
        gload16(Brow + t * 32, (char*)ldsu + buf * 24576 + 16384 + wid * 1024);
    };

    const int rslot = ((l15 & 1) * 4 + lhi) ^ ((l15 >> 1) & 7);
    const int fragoff = (l15 >> 1) * 64 + rslot * 8;

    f32x4 acc[8][2];
#pragma unroll
    for (int i = 0; i < 8; ++i) {
        acc[i][0] = (f32x4){0.f, 0.f, 0.f, 0.f};
        acc[i][1] = (f32x4){0.f, 0.f, 0.f, 0.f};
    }

    auto doTile = [&](int cur, int tstage, bool dostage) {
        const u16* Ab = ldsu + cur * 12288 + wr * 4096 + fragoff;
        const u16* Bb = ldsu + cur * 12288 + 8192 + wc * 1024 + fragoff;
        bf16x8 af[8], b0, b1;
#pragma unroll
        for (int mf = 0; mf < 8; ++mf) af[mf] = *(const bf16x8*)(Ab + mf * 512);
        b0 = *(const bf16x8*)(Bb);
        b1 = *(const bf16x8*)(Bb + 512);
        if (dostage) stageA(tstage & 3, tstage);
        __builtin_amdgcn_s_setprio(1);
#pragma unroll
        for (int mf = 0; mf < 8; ++mf) acc[mf][0] = MFMA16(af[mf], b0, acc[mf][0]);
        __builtin_amdgcn_s_setprio(0);
        if (dostage) stageB(tstage & 3, tstage);
        __builtin_amdgcn_s_setprio(1);
#pragma unroll
        for (int mf = 0; mf < 8; ++mf) acc[mf][1] = MFMA16(af[mf], b1, acc[mf][1]);
        __builtin_amdgcn_s_setprio(0);
    };

    stageA(0, 0); stageB(0, 0);
    stageA(1, 1); stageB(1, 1);
    stageA(2, 2); stageB(2, 2);
    asm volatile("s_waitcnt vmcnt(6)" ::: "memory");
    __builtin_amdgcn_s_barrier();
    __builtin_amdgcn_sched_barrier(0);

    for (int t = 0; t < NT - 3; ++t) {
        doTile(t & 3, t + 3, true);
        asm volatile("s_waitcnt vmcnt(6)" ::: "memory");
        __builtin_amdgcn_s_barrier();
        __builtin_amdgcn_sched_barrier(0);
    }
    doTile((NT - 3) & 3, 0, false);
    asm volatile("s_waitcnt vmcnt(3)" ::: "memory");
    __builtin_amdgcn_s_barrier();
    __builtin_amdgcn_sched_barrier(0);
    doTile((NT - 2) & 3, 0, false);
    asm volatile("s_waitcnt vmcnt(0)" ::: "memory");
    __builtin_amdgcn_s_barrier();
    __builtin_amdgcn_sched_barrier(0);
    doTile((NT - 1) & 3, 0, false);

#pragma unroll
    for (int nf = 0; nf < 2; ++nf) {
        int cg = bn * 128 + wc * 32 + nf * 16 + l15;
        float bv = bias[cg];
#pragma unroll
        for (int mf = 0; mf < 8; ++mf) {
            int rgb = bm * 256 + wr * 128 + mf * 16 + lhi * 4;
#pragma unroll
            for (int v = 0; v < 4; ++v)
                outf[(size_t)(rgb + v) * 1024 + cg] = acc[mf][nf][v] + bv;
        }
    }
}

// ---------------------------------------------------------------------------
// Flash attention fwd, causal — 16x16x32 swapped-operand (verified r5/r7/r8/r9).
__global__ __launch_bounds__(256, 4) void attn_kernel(
    const u16* __restrict__ qbuf, const u16* __restrict__ kbuf,
    const u16* __restrict__ vtb, u16* __restrict__ obuf) {
    __shared__ u16 Kl[2][64 * 64];
    __shared__ u16 Vl[2][64 * 64];
    const int bid = blockIdx.x;
    const int rr = bid >> 8;
    const int pp = (bid >> 6) & 3;
    const int c = (rr & 1) ? (((rr >> 1) << 2) + pp)
                           : (15 - ((rr >> 1) << 2) - pp);
    const int bh = ((bid & 7) << 3) + ((bid >> 3) & 7);
    const int b = bh >> 4, h = bh & 15;
    const int tid = threadIdx.x, wid = tid >> 6, lane = tid & 63;
    const int l15 = lane & 15, lhi = lane >> 4;
    const int q0 = c * 128 + wid * 32;
    const int ntW = 2 * c + (wid >> 1) + 1;
    const int ntmax = 2 * c + 2;

    auto loadQ = [&](int qbase, bf16x8* dst) {
        const u16* qp = qbuf + ((size_t)bh * 2048 + qbase + l15) * 64 + lhi * 8;
        dst[0] = *(const bf16x8*)(qp);
        dst[1] = *(const bf16x8*)(qp + 32);
    };
    bf16x8 qf0[2], qf1[2];
    loadQ(q0, qf0); loadQ(q0 + 16, qf1);

    float m0 = -1e30f, l0 = 0.f, m1 = -1e30f, l1 = 0.f;
    f32x4 o0[4], o1[4];
#pragma unroll
    for (int d = 0; d < 4; ++d) {
        o0[d] = (f32x4){0.f, 0.f, 0.f, 0.f};
        o1[d] = (f32x4){0.f, 0.f, 0.f, 0.f};
    }

    const int srow = lane >> 3;
    const int scolb = ((lane & 7) * 16) ^ (srow << 4);

    auto stage = [&](int buf, int t) {
        const int kbase = t * 64;
#pragma unroll
        for (int s = 0; s < 2; ++s) {
            int sg = wid * 2 + s;
            int row = sg * 8 + srow;
            const u16* gk = kbuf + ((size_t)bh * 2048 + kbase + row) * 64 + (scolb >> 1);
            gload16(gk, (char*)Kl[buf] + sg * 1024);
            const u16* gv = vtb + ((size_t)bh * 64 + row) * 2048 + kbase + (scolb >> 1);
            gload16(gv, (char*)Vl[buf] + sg * 1024);
        }
    };

    auto smax = [&](f32x4* s, int qg0, int t, float& m, float& l, f32x4* oa, u32* pw) {
        const int qg = qg0 + l15;
        if (64 * t + 63 > qg0) {
#pragma unroll
            for (int kb4 = 0; kb4 < 4; ++kb4)
#pragma unroll
                for (int v = 0; v < 4; ++v) {
                    int kg = 64 * t + kb4 * 16 + lhi * 4 + v;
                    if (kg > qg) s[kb4][v] = -1e30f;
                }
        }
        float pm = fmaxf(fmaxf(fmaxf(s[0][0], s[0][1]), fmaxf(s[0][2], s[0][3])),
                         fmaxf(fmaxf(s[1][0], s[1][1]), fmaxf(s[1][2], s[1][3])));
        pm = fmaxf(pm, fmaxf(fmaxf(fmaxf(s[2][0], s[2][1]), fmaxf(s[2][2], s[2][3])),
                             fmaxf(fmaxf(s[3][0], s[3][1]), fmaxf(s[3][2], s[3][3]))));
        pm = redmax_cross(pm);
        if (!__all(pm <= m + 8.f)) {
            float nm = fmaxf(m, pm);
            float f = exp2f(m - nm);
            m = nm;
            l *= f;
#pragma unroll
            for (int d = 0; d < 4; ++d)
#pragma unroll
                for (int v = 0; v < 4; ++v) oa[d][v] *= f;
        }
        float rs = 0.f;
#pragma unroll
        for (int kb4 = 0; kb4 < 4; ++kb4)
#pragma unroll
            for (int v = 0; v < 4; ++v) {
                float e = exp2f(s[kb4][v] - m);
                s[kb4][v] = e;
                rs += e;
            }
        l += redsum_cross(rs);
        pw[0] = pkbf(s[0][0], s[0][1]); pw[1] = pkbf(s[0][2], s[0][3]);
        pw[2] = pkbf(s[1][0], s[1][1]); pw[3] = pkbf(s[1][2], s[1][3]);
        pw[4] = pkbf(s[2][0], s[2][1]); pw[5] = pkbf(s[2][2], s[2][3]);
        pw[6] = pkbf(s[3][0], s[3][1]); pw[7] = pkbf(s[3][2], s[3][3]);
    };

    auto computeChunk = [&](const char* Kb, const char* Vb, int t) {
        f32x4 s0[4], s1[4];
        __builtin_amdgcn_s_setprio(1);
#pragma unroll
        for (int kb4 = 0; kb4 < 4; ++kb4) {
            const int r = kb4 * 16 + l15;
            const int sw = (r & 7) << 4;
            const int rowb = r * 128;
            bf16x8 kf0 = *(const bf16x8*)(Kb + rowb + ((lhi * 16) ^ sw));
            bf16x8 kf1 = *(const bf16x8*)(Kb + rowb + ((64 + lhi * 16) ^ sw));
            f32x4 a0 = (f32x4){0.f, 0.f, 0.f, 0.f};
            a0 = MFMA16(kf0, qf0[0], a0);
            a0 = MFMA16(kf1, qf0[1], a0);
            s0[kb4] = a0;
            f32x4 a1 = (f32x4){0.f, 0.f, 0.f, 0.f};
            a1 = MFMA16(kf0, qf1[0], a1);
            a1 = MFMA16(kf1, qf1[1], a1);
            s1[kb4] = a1;
        }
        __builtin_amdgcn_s_setprio(0);
        u32 pw0[8], pw1[8];
        smax(s0, q0, t, m0, l0, o0, pw0);
        smax(s1, q0 + 16, t, m1, l1, o1, pw1);
        __builtin_amdgcn_s_setprio(1);
#pragma unroll
        for (int ks = 0; ks < 2; ++ks) {
            bf16x8 pb0 = __builtin_bit_cast(bf16x8,
                (u32x4){pw0[ks * 4 + 0], pw0[ks * 4 + 1], pw0[ks * 4 + 2], pw0[ks * 4 + 3]});
            bf16x8 pb1 = __builtin_bit_cast(bf16x8,
                (u32x4){pw1[ks * 4 + 0], pw1[ks * 4 + 1], pw1[ks * 4 + 2], pw1[ks * 4 + 3]});
#pragma unroll
            for (int dhb = 0; dhb < 4; ++dhb) {
                const int r = dhb * 16 + l15;
                const int sw = (r & 7) << 4;
                u16x4 v0 = *(const u16x4*)(Vb + r * 128 + ((ks * 64 + 8 * lhi) ^ sw));
                u16x4 v1 = *(const u16x4*)(Vb + r * 128 + ((ks * 64 + 32 + 8 * lhi) ^ sw));
                u16x8 vv = {v0[0], v0[1], v0[2], v0[3], v1[0], v1[1], v1[2], v1[3]};
                bf16x8 vf = __builtin_bit_cast(bf16x8, vv);
                o0[dhb] = MFMA16(vf, pb0, o0[dhb]);
                o1[dhb] = MFMA16(vf, pb1, o1[dhb]);
            }
        }
        __builtin_amdgcn_s_setprio(0);
    };

    stage(0, 0);
    int t = 0;
    for (;;) {
        __syncthreads();
        if (t + 1 < ntmax) stage(1, t + 1);
        if (t < ntW) computeChunk((const char*)Kl[0], (const char*)Vl[0], t);
        if (++t == ntmax) break;
        __syncthreads();
        if (t + 1 < ntmax) stage(0, t + 1);
        if (t < ntW) computeChunk((const char*)Kl[1], (const char*)Vl[1], t);
        if (++t == ntmax) break;
    }

    auto epi = [&](int qg0, float l, const f32x4* oa) {
        const float rl = 1.f / l;
        const int q = qg0 + l15;
        const size_t rowoff = ((size_t)b * 2048 + q) * 1024 + h * 64;
#pragma unroll
        for (int dhb = 0; dhb < 4; ++dhb) {
            u16x4 w;
#pragma unroll
            for (int v = 0; v < 4; ++v) w[v] = f2bf(oa[dhb][v] * rl);
            *(u16x4*)&obuf[rowoff + dhb * 16 + lhi * 4] = w;
        }
    };
    epi(q0, l0, o0);
    epi(q0 + 16, l1, o1);
}

// ---------------------------------------------------------------------------
extern "C" void kernel_launch(void* const* d_in, const int* in_sizes, int n_in,
                              void* d_out, int out_size, void* d_ws, size_t ws_size,
                              hipStream_t stream) {
    const float* inp   = (const float*)d_in[0];   // [4,2048,1024]
    const float* W_qkv = (const float*)d_in[1];   // [1024,3072]
    const float* b_qkv = (const float*)d_in[2];   // [3072]
    const float* W_out = (const float*)d_in[3];   // [1024,1024]
    const float* b_out = (const float*)d_in[4];   // [1024]
    float* out = (float*)d_out;                   // [4,2048,1024] f32

    u16* xb   = (u16*)d_ws;          // 8192x1024
    u16* wqt  = xb + 8388608;        // 3072x1024
    u16* wot  = wqt + 3145728;       // 1024x1024
    u16* qbuf = wot + 1048576;       // [64][2048][64]
    u16* kbuf = qbuf + 8388608;
    u16* vbuf = kbuf + 8388608;
    u16* vtb  = vbuf + 8388608;      // [64][64][2048]
    u16* obuf = vtb + 8388608;       // 8192x1024

    convert_f32_bf16<<<8192, 256, 0, stream>>>(inp, xb, 2097152);
    transpose_convert<<<dim3(16, 48), 256, 0, stream>>>(W_qkv, wqt, 1024, 3072);
    transpose_convert<<<dim3(16, 16), 256, 0, stream>>>(W_out, wot, 1024, 1024);
    gemm256_qkv<<<768, 512, 0, stream>>>(xb, wqt, b_qkv, qbuf, kbuf, vbuf);
    transpose_v<<<dim3(32, 64), 256, 0, stream>>>(vbuf, vtb);
    attn_kernel<<<1024, 256, 0, stream>>>(qbuf, kbuf, vtb, obuf);
    gemm256_out<<<256, 512, 0, stream>>>(obuf, wot, b_out, out);
}

// Round 11
// 186.467 us; speedup vs baseline: 1.0002x; 1.0002x over previous
//
#include <hip/hip_runtime.h>
#include <hip/hip_bf16.h>

typedef unsigned short u16;
typedef unsigned u32;
typedef __attribute__((ext_vector_type(4))) unsigned short u16x4;
typedef __attribute__((ext_vector_type(8))) unsigned short u16x8;
typedef __attribute__((ext_vector_type(4))) unsigned u32x4;
typedef __attribute__((ext_vector_type(8))) __bf16 bf16x8;
typedef __attribute__((ext_vector_type(4))) float f32x4;

typedef __attribute__((address_space(1))) void as1v;
typedef __attribute__((address_space(3))) void as3v;

#define MFMA16(a, b, c) __builtin_amdgcn_mfma_f32_16x16x32_bf16(a, b, c, 0, 0, 0)

#if __has_builtin(__builtin_amdgcn_permlane16_swap) && __has_builtin(__builtin_amdgcn_permlane32_swap)
#define HAVE_PERMLANE_SWAP 1
#else
#define HAVE_PERMLANE_SWAP 0
#endif

__device__ __forceinline__ u16 f2bf(float f) {
    unsigned u = __builtin_bit_cast(unsigned, f);
    u += 0x7fffu + ((u >> 16) & 1u);
    return (u16)(u >> 16);
}

__device__ __forceinline__ u32 pkbf(float lo, float hi) {
    u32 r;
    asm("v_cvt_pk_bf16_f32 %0, %1, %2" : "=v"(r) : "v"(lo), "v"(hi));
    return r;
}

__device__ __forceinline__ void gload16(const void* g, void* l) {
    __builtin_amdgcn_global_load_lds((as1v*)g, (as3v*)l, 16, 0, 0);
}

// cross-lane reduce over lanes {l, l^16, l^32, l^48} — direction-proof.
__device__ __forceinline__ float redmax_cross(float v) {
#if HAVE_PERMLANE_SWAP
    u32 xu = __builtin_bit_cast(u32, v);
    auto r16 = __builtin_amdgcn_permlane16_swap(xu, xu, false, false);
    float a = fmaxf(__builtin_bit_cast(float, (u32)r16[0]),
                    __builtin_bit_cast(float, (u32)r16[1]));
    u32 au = __builtin_bit_cast(u32, a);
    auto r32 = __builtin_amdgcn_permlane32_swap(au, au, false, false);
    return fmaxf(__builtin_bit_cast(float, (u32)r32[0]),
                 __builtin_bit_cast(float, (u32)r32[1]));
#else
    v = fmaxf(v, __shfl_xor(v, 16, 64));
    return fmaxf(v, __shfl_xor(v, 32, 64));
#endif
}

__device__ __forceinline__ float redsum_cross(float v) {
#if HAVE_PERMLANE_SWAP
    u32 xu = __builtin_bit_cast(u32, v);
    auto r16 = __builtin_amdgcn_permlane16_swap(xu, xu, false, false);
    float a = __builtin_bit_cast(float, (u32)r16[0]) +
              __builtin_bit_cast(float, (u32)r16[1]);
    u32 au = __builtin_bit_cast(u32, a);
    auto r32 = __builtin_amdgcn_permlane32_swap(au, au, false, false);
    return __builtin_bit_cast(float, (u32)r32[0]) +
           __builtin_bit_cast(float, (u32)r32[1]);
#else
    v += __shfl_xor(v, 16, 64);
    return v + __shfl_xor(v, 32, 64);
#endif
}

// ---------------------------------------------------------------------------
__global__ void convert_f32_bf16(const float* __restrict__ in, u16* __restrict__ out, int n4) {
    int i = blockIdx.x * blockDim.x + threadIdx.x;
    if (i < n4) {
        float4 v = *(const float4*)&in[(size_t)i * 4];
        u16x4 o;
        o.x = f2bf(v.x); o.y = f2bf(v.y); o.z = f2bf(v.z); o.w = f2bf(v.w);
        *(u16x4*)&out[(size_t)i * 4] = o;
    }
}

// ---------------------------------------------------------------------------
__global__ void transpose_convert(const float* __restrict__ in, u16* __restrict__ out, int R, int C) {
    __shared__ float tl[64][65];
    const int rb = blockIdx.x, cb = blockIdx.y;
    const int tid = threadIdx.x;
    for (int it = 0; it < 4; ++it) {
        int lin = (tid + it * 256) * 4;
        int r = lin >> 6, c = lin & 63;
        float4 v = *(const float4*)&in[(size_t)(rb * 64 + r) * C + cb * 64 + c];
        tl[r][c + 0] = v.x; tl[r][c + 1] = v.y; tl[r][c + 2] = v.z; tl[r][c + 3] = v.w;
    }
    __syncthreads();
    for (int it = 0; it < 4; ++it) {
        int lin = (tid + it * 256) * 4;
        int oc = lin >> 6, orr = lin & 63;
        u16x4 o;
        o.x = f2bf(tl[orr + 0][oc]);
        o.y = f2bf(tl[orr + 1][oc]);
        o.z = f2bf(tl[orr + 2][oc]);
        o.w = f2bf(tl[orr + 3][oc]);
        *(u16x4*)&out[(size_t)(cb * 64 + oc) * R + rb * 64 + orr] = o;
    }
}

// ---------------------------------------------------------------------------
// QKV projection GEMM, deep-pipelined 256x128 tile (r10-verified skeleton).
// M=8192, N=3072, K=1024. Grid 768 = 3 exact dispatch rounds at 1 block/CU.
// Epilogue: Q/K -> LDS-staged coalesced stores into [b,h][n][64] (r10-verified);
// V -> DIRECT TRANSPOSED scatter into vtb[b,h][dh][n] (replaces transpose_v).
__global__ __launch_bounds__(512, 2) void gemm256_qkv(
    const u16* __restrict__ A, const u16* __restrict__ Bt, const float* __restrict__ bias,
    u16* __restrict__ qb, u16* __restrict__ kb, u16* __restrict__ vtb) {
    constexpr int K = 1024;
    constexpr int NT = 32;
    __shared__ u16 ldsu[49152];   // 96 KB

    const int bid = blockIdx.x;
    const int swz = (bid & 7) * 96 + (bid >> 3);   // XCD-contiguous
    const int bm = swz / 24, bn = swz % 24;

    const int tid = threadIdx.x, wid = tid >> 6, lane = tid & 63;
    const int wr = wid >> 2, wc = wid & 3;
    const int l15 = lane & 15, lhi = lane >> 4;

    const int sslot = (lane & 7) ^ (lane >> 3);
    const int kcol = (sslot & 3) * 8;
    const int mloc = (lane >> 3) * 2 + (sslot >> 2);

    const u16* Arow[2];
#pragma unroll
    for (int li = 0; li < 2; ++li) {
        int sg = wid * 2 + li;
        Arow[li] = A + (size_t)(bm * 256 + sg * 16 + mloc) * K + kcol;
    }
    const u16* Brow = Bt + (size_t)(bn * 128 + wid * 16 + mloc) * K + kcol;

    auto stageA = [&](int buf, int t) {
#pragma unroll
        for (int li = 0; li < 2; ++li) {
            int sg = wid * 2 + li;
            gload16(Arow[li] + t * 32, (char*)ldsu + buf * 24576 + sg * 1024);
        }
    };
    auto stageB = [&](int buf, int t) {
        gload16(Brow + t * 32, (char*)ldsu + buf * 24576 + 16384 + wid * 1024);
    };

    const int rslot = ((l15 & 1) * 4 + lhi) ^ ((l15 >> 1) & 7);
    const int fragoff = (l15 >> 1) * 64 + rslot * 8;

    f32x4 acc[8][2];
#pragma unroll
    for (int i = 0; i < 8; ++i) {
        acc[i][0] = (f32x4){0.f, 0.f, 0.f, 0.f};
        acc[i][1] = (f32x4){0.f, 0.f, 0.f, 0.f};
    }

    auto doTile = [&](int cur, int tstage, bool dostage) {
        const u16* Ab = ldsu + cur * 12288 + wr * 4096 + fragoff;
        const u16* Bb = ldsu + cur * 12288 + 8192 + wc * 1024 + fragoff;
        bf16x8 af[8], b0, b1;
#pragma unroll
        for (int mf = 0; mf < 8; ++mf) af[mf] = *(const bf16x8*)(Ab + mf * 512);
        b0 = *(const bf16x8*)(Bb);
        b1 = *(const bf16x8*)(Bb + 512);
        if (dostage) stageA(tstage & 3, tstage);
        __builtin_amdgcn_s_setprio(1);
#pragma unroll
        for (int mf = 0; mf < 8; ++mf) acc[mf][0] = MFMA16(af[mf], b0, acc[mf][0]);
        __builtin_amdgcn_s_setprio(0);
        if (dostage) stageB(tstage & 3, tstage);
        __builtin_amdgcn_s_setprio(1);
#pragma unroll
        for (int mf = 0; mf < 8; ++mf) acc[mf][1] = MFMA16(af[mf], b1, acc[mf][1]);
        __builtin_amdgcn_s_setprio(0);
    };

    stageA(0, 0); stageB(0, 0);
    stageA(1, 1); stageB(1, 1);
    stageA(2, 2); stageB(2, 2);
    asm volatile("s_waitcnt vmcnt(6)" ::: "memory");
    __builtin_amdgcn_s_barrier();
    __builtin_amdgcn_sched_barrier(0);

    for (int t = 0; t < NT - 3; ++t) {
        doTile(t & 3, t + 3, true);
        asm volatile("s_waitcnt vmcnt(6)" ::: "memory");
        __builtin_amdgcn_s_barrier();
        __builtin_amdgcn_sched_barrier(0);
    }
    doTile((NT - 3) & 3, 0, false);
    asm volatile("s_waitcnt vmcnt(3)" ::: "memory");
    __builtin_amdgcn_s_barrier();
    __builtin_amdgcn_sched_barrier(0);
    doTile((NT - 2) & 3, 0, false);
    asm volatile("s_waitcnt vmcnt(0)" ::: "memory");
    __builtin_amdgcn_s_barrier();
    __builtin_amdgcn_sched_barrier(0);
    doTile((NT - 1) & 3, 0, false);

    // ---- epilogue ----
    __syncthreads();   // all pipeline LDS reads done before any LDS reuse
    const int cg0 = bn * 128 + wc * 32;        // wave's 32-col group
    const int which = cg0 >> 10, rem = cg0 & 1023;
    const int hh = rem >> 6, dh0 = rem & 63;
    const int rgb0 = bm * 256 + wr * 128;
    const int bb = rgb0 >> 11, n0 = rgb0 & 2047;
    float bv0 = bias[cg0 + l15], bv1 = bias[cg0 + 16 + l15];

    if (which == 2) {
        // V: direct transposed scatter into vtb[b,h][dh][n]
        const size_t vbase = ((size_t)(bb * 16 + hh) * 64 + dh0) * 2048 + (size_t)n0;
#pragma unroll
        for (int nf = 0; nf < 2; ++nf) {
            float bv = (nf == 0) ? bv0 : bv1;
            size_t rowb = vbase + (size_t)(nf * 16 + l15) * 2048;
#pragma unroll
            for (int mf = 0; mf < 8; ++mf) {
                u16x4 w;
#pragma unroll
                for (int v = 0; v < 4; ++v) w[v] = f2bf(acc[mf][nf][v] + bv);
                *(u16x4*)&vtb[rowb + mf * 16 + lhi * 4] = w;
            }
        }
    } else {
        // Q/K: LDS-staged coalesced stores (r10-verified path)
        u16* dst = (which == 0) ? qb : kb;
        const float qs = (which == 0) ? 0.18033688011112042f : 1.0f;  // 0.125*log2e
        char* lep = (char*)ldsu + wid * 8192;
#pragma unroll
        for (int mf = 0; mf < 8; ++mf)
#pragma unroll
            for (int v = 0; v < 4; ++v) {
                int row = mf * 16 + lhi * 4 + v;
                int sw = ((row >> 2) & 3) << 4;
                *(u16*)(lep + row * 64 + ((l15 * 2) ^ sw)) =
                    f2bf((acc[mf][0][v] + bv0) * qs);
                *(u16*)(lep + row * 64 + ((32 + l15 * 2) ^ sw)) =
                    f2bf((acc[mf][1][v] + bv1) * qs);
            }
        const size_t gbase = (((size_t)bb * 16 + hh) * 2048 + n0) * 64 + dh0;
#pragma unroll
        for (int it = 0; it < 8; ++it) {
            int idx = it * 64 + lane;
            int row = idx >> 2, j = idx & 3;
            u16x8 vv = *(const u16x8*)(lep + row * 64 + ((j * 16) ^ (((row >> 2) & 3) << 4)));
            *(u16x8*)&dst[gbase + (size_t)row * 64 + j * 8] = vv;
        }
    }
}

// ---------------------------------------------------------------------------
// Output projection GEMM, deep-pipelined 256x128 tile (verified r9/r10).
__global__ __launch_bounds__(512, 2) void gemm256_out(
    const u16* __restrict__ A, const u16* __restrict__ Bt, const float* __restrict__ bias,
    float* __restrict__ outf) {
    constexpr int K = 1024;
    constexpr int NT = 32;
    __shared__ u16 ldsu[49152];   // 96 KB

    const int bid = blockIdx.x;
    const int swz = (bid & 7) * 32 + (bid >> 3);   // XCD-contiguous bm
    const int bm = swz >> 3, bn = swz & 7;

    const int tid = threadIdx.x, wid = tid >> 6, lane = tid & 63;
    const int wr = wid >> 2, wc = wid & 3;
    const int l15 = lane & 15, lhi = lane >> 4;

    const int sslot = (lane & 7) ^ (lane >> 3);
    const int kcol = (sslot & 3) * 8;
    const int mloc = (lane >> 3) * 2 + (sslot >> 2);

    const u16* Arow[2];
#pragma unroll
    for (int li = 0; li < 2; ++li) {
        int sg = wid * 2 + li;
        Arow[li] = A + (size_t)(bm * 256 + sg * 16 + mloc) * K + kcol;
    }
    const u16* Brow = Bt + (size_t)(bn * 128 + wid * 16 + mloc) * K + kcol;

    auto stageA = [&](int buf, int t) {
#pragma unroll
        for (int li = 0; li < 2; ++li) {
            int sg = wid * 2 + li;
            gload16(Arow[li] + t * 32, (char*)ldsu + buf * 24576 + sg * 1024);
        }
    };
    auto stageB = [&](int buf, int t) {
        gload16(Brow + t * 32, (char*)ldsu + buf * 24576 + 16384 + wid * 1024);
    };

    const int rslot = ((l15 & 1) * 4 + lhi) ^ ((l15 >> 1) & 7);
    const int fragoff = (l15 >> 1) * 64 + rslot * 8;

    f32x4 acc[8][2];
#pragma unroll
    for (int i = 0; i < 8; ++i) {
        acc[i][0] = (f32x4){0.f, 0.f, 0.f, 0.f};
        acc[i][1] = (f32x4){0.f, 0.f, 0.f, 0.f};
    }

    auto doTile = [&](int cur, int tstage, bool dostage) {
        const u16* Ab = ldsu + cur * 12288 + wr * 4096 + fragoff;
        const u16* Bb = ldsu + cur * 12288 + 8192 + wc * 1024 + fragoff;
        bf16x8 af[8], b0, b1;
#pragma unroll
        for (int mf = 0; mf < 8; ++mf) af[mf] = *(const bf16x8*)(Ab + mf * 512);
        b0 = *(const bf16x8*)(Bb);
        b1 = *(const bf16x8*)(Bb + 512);
        if (dostage) stageA(tstage & 3, tstage);
        __builtin_amdgcn_s_setprio(1);
#pragma unroll
        for (int mf = 0; mf < 8; ++mf) acc[mf][0] = MFMA16(af[mf], b0, acc[mf][0]);
        __builtin_amdgcn_s_setprio(0);
        if (dostage) stageB(tstage & 3, tstage);
        __builtin_amdgcn_s_setprio(1);
#pragma unroll
        for (int mf = 0; mf < 8; ++mf) acc[mf][1] = MFMA16(af[mf], b1, acc[mf][1]);
        __builtin_amdgcn_s_setprio(0);
    };

    stageA(0, 0); stageB(0, 0);
    stageA(1, 1); stageB(1, 1);
    stageA(2, 2); stageB(2, 2);
    asm volatile("s_waitcnt vmcnt(6)" ::: "memory");
    __builtin_amdgcn_s_barrier();
    __builtin_amdgcn_sched_barrier(0);

    for (int t = 0; t < NT - 3; ++t) {
        doTile(t & 3, t + 3, true);
        asm volatile("s_waitcnt vmcnt(6)" ::: "memory");
        __builtin_amdgcn_s_barrier();
        __builtin_amdgcn_sched_barrier(0);
    }
    doTile((NT - 3) & 3, 0, false);
    asm volatile("s_waitcnt vmcnt(3)" ::: "memory");
    __builtin_amdgcn_s_barrier();
    __builtin_amdgcn_sched_barrier(0);
    doTile((NT - 2) & 3, 0, false);
    asm volatile("s_waitcnt vmcnt(0)" ::: "memory");
    __builtin_amdgcn_s_barrier();
    __builtin_amdgcn_sched_barrier(0);
    doTile((NT - 1) & 3, 0, false);

#pragma unroll
    for (int nf = 0; nf < 2; ++nf) {
        int cg = bn * 128 + wc * 32 + nf * 16 + l15;
        float bv = bias[cg];
#pragma unroll
        for (int mf = 0; mf < 8; ++mf) {
            int rgb = bm * 256 + wr * 128 + mf * 16 + lhi * 4;
#pragma unroll
            for (int v = 0; v < 4; ++v)
                outf[(size_t)(rgb + v) * 1024 + cg] = acc[mf][nf][v] + bv;
        }
    }
}

// ---------------------------------------------------------------------------
// Flash attention fwd, causal — 16x16x32 swapped-operand (verified r5/r7-r10).
// Round 11: softmax row-sum moved onto the matrix pipe (ones-row A-operand:
// 2 extra MFMA/group accumulate l = sum_k P into a dedicated acc whose
// non-row-0 slots stay exactly 0); max-tree restructured into v_max3 triples.
__global__ __launch_bounds__(256, 4) void attn_kernel(
    const u16* __restrict__ qbuf, const u16* __restrict__ kbuf,
    const u16* __restrict__ vtb, u16* __restrict__ obuf) {
    __shared__ u16 Kl[2][64 * 64];
    __shared__ u16 Vl[2][64 * 64];
    const int bid = blockIdx.x;
    const int rr = bid >> 8;
    const int pp = (bid >> 6) & 3;
    const int c = (rr & 1) ? (((rr >> 1) << 2) + pp)
                           : (15 - ((rr >> 1) << 2) - pp);
    const int bh = ((bid & 7) << 3) + ((bid >> 3) & 7);
    const int b = bh >> 4, h = bh & 15;
    const int tid = threadIdx.x, wid = tid >> 6, lane = tid & 63;
    const int l15 = lane & 15, lhi = lane >> 4;
    const int q0 = c * 128 + wid * 32;
    const int ntW = 2 * c + (wid >> 1) + 1;
    const int ntmax = 2 * c + 2;

    auto loadQ = [&](int qbase, bf16x8* dst) {
        const u16* qp = qbuf + ((size_t)bh * 2048 + qbase + l15) * 64 + lhi * 8;
        dst[0] = *(const bf16x8*)(qp);
        dst[1] = *(const bf16x8*)(qp + 32);
    };
    bf16x8 qf0[2], qf1[2];
    loadQ(q0, qf0); loadQ(q0 + 16, qf1);

    // ones-row A-operand: row 0 of a 16x32 block = 1.0, rest 0.
    bf16x8 onesA;
    {
        u16x8 ov;
        u16 o = (l15 == 0) ? (u16)0x3F80 : (u16)0;
#pragma unroll
        for (int j = 0; j < 8; ++j) ov[j] = o;
        onesA = __builtin_bit_cast(bf16x8, ov);
    }

    float m0 = -1e30f, m1 = -1e30f;
    f32x4 o0[4], o1[4], lac0, lac1;
#pragma unroll
    for (int d = 0; d < 4; ++d) {
        o0[d] = (f32x4){0.f, 0.f, 0.f, 0.f};
        o1[d] = (f32x4){0.f, 0.f, 0.f, 0.f};
    }
    lac0 = (f32x4){0.f, 0.f, 0.f, 0.f};
    lac1 = (f32x4){0.f, 0.f, 0.f, 0.f};

    const int srow = lane >> 3;
    const int scolb = ((lane & 7) * 16) ^ (srow << 4);

    auto stage = [&](int buf, int t) {
        const int kbase = t * 64;
#pragma unroll
        for (int s = 0; s < 2; ++s) {
            int sg = wid * 2 + s;
            int row = sg * 8 + srow;
            const u16* gk = kbuf + ((size_t)bh * 2048 + kbase + row) * 64 + (scolb >> 1);
            gload16(gk, (char*)Kl[buf] + sg * 1024);
            const u16* gv = vtb + ((size_t)bh * 64 + row) * 2048 + kbase + (scolb >> 1);
            gload16(gv, (char*)Vl[buf] + sg * 1024);
        }
    };

    // masking + online max + P-pack for one 16-q group (defer-max THR=8).
    // Row-sum is NOT computed here — it rides the PV MFMA via onesA.
    auto smax = [&](f32x4* s, int qg0, int t, float& m, f32x4& lac, f32x4* oa, u32* pw) {
        const int qg = qg0 + l15;
        if (64 * t + 63 > qg0) {
#pragma unroll
            for (int kb4 = 0; kb4 < 4; ++kb4)
#pragma unroll
                for (int v = 0; v < 4; ++v) {
                    int kg = 64 * t + kb4 * 16 + lhi * 4 + v;
                    if (kg > qg) s[kb4][v] = -1e30f;
                }
        }
        // v_max3-friendly triples: 16 values in 8 ops
        float f1 = fmaxf(fmaxf(s[0][0], s[0][1]), s[0][2]);
        float f2 = fmaxf(fmaxf(s[0][3], s[1][0]), s[1][1]);
        float f3 = fmaxf(fmaxf(s[1][2], s[1][3]), s[2][0]);
        float f4 = fmaxf(fmaxf(s[2][1], s[2][2]), s[2][3]);
        float f5 = fmaxf(fmaxf(s[3][0], s[3][1]), s[3][2]);
        float g1 = fmaxf(fmaxf(f1, f2), f3);
        float g2 = fmaxf(fmaxf(f4, f5), s[3][3]);
        float pm = redmax_cross(fmaxf(g1, g2));
        if (!__all(pm <= m + 8.f)) {
            float nm = fmaxf(m, pm);
            float f = exp2f(m - nm);
            m = nm;
#pragma unroll
            for (int v = 0; v < 4; ++v) lac[v] *= f;
#pragma unroll
            for (int d = 0; d < 4; ++d)
#pragma unroll
                for (int v = 0; v < 4; ++v) oa[d][v] *= f;
        }
#pragma unroll
        for (int kb4 = 0; kb4 < 4; ++kb4)
#pragma unroll
            for (int v = 0; v < 4; ++v) s[kb4][v] = exp2f(s[kb4][v] - m);
        pw[0] = pkbf(s[0][0], s[0][1]); pw[1] = pkbf(s[0][2], s[0][3]);
        pw[2] = pkbf(s[1][0], s[1][1]); pw[3] = pkbf(s[1][2], s[1][3]);
        pw[4] = pkbf(s[2][0], s[2][1]); pw[5] = pkbf(s[2][2], s[2][3]);
        pw[6] = pkbf(s[3][0], s[3][1]); pw[7] = pkbf(s[3][2], s[3][3]);
    };

    // 2 groups vs tile t; K/V fragments read once, used twice
    auto computeChunk = [&](const char* Kb, const char* Vb, int t) {
        f32x4 s0[4], s1[4];
        __builtin_amdgcn_s_setprio(1);
#pragma unroll
        for (int kb4 = 0; kb4 < 4; ++kb4) {
            const int r = kb4 * 16 + l15;
            const int sw = (r & 7) << 4;
            const int rowb = r * 128;
            bf16x8 kf0 = *(const bf16x8*)(Kb + rowb + ((lhi * 16) ^ sw));
            bf16x8 kf1 = *(const bf16x8*)(Kb + rowb + ((64 + lhi * 16) ^ sw));
            f32x4 a0 = (f32x4){0.f, 0.f, 0.f, 0.f};
            a0 = MFMA16(kf0, qf0[0], a0);
            a0 = MFMA16(kf1, qf0[1], a0);
            s0[kb4] = a0;
            f32x4 a1 = (f32x4){0.f, 0.f, 0.f, 0.f};
            a1 = MFMA16(kf0, qf1[0], a1);
            a1 = MFMA16(kf1, qf1[1], a1);
            s1[kb4] = a1;
        }
        __builtin_amdgcn_s_setprio(0);
        u32 pw0[8], pw1[8];
        smax(s0, q0, t, m0, lac0, o0, pw0);
        smax(s1, q0 + 16, t, m1, lac1, o1, pw1);
        __builtin_amdgcn_s_setprio(1);
#pragma unroll
        for (int ks = 0; ks < 2; ++ks) {
            bf16x8 pb0 = __builtin_bit_cast(bf16x8,
                (u32x4){pw0[ks * 4 + 0], pw0[ks * 4 + 1], pw0[ks * 4 + 2], pw0[ks * 4 + 3]});
            bf16x8 pb1 = __builtin_bit_cast(bf16x8,
                (u32x4){pw1[ks * 4 + 0], pw1[ks * 4 + 1], pw1[ks * 4 + 2], pw1[ks * 4 + 3]});
#pragma unroll
            for (int dhb = 0; dhb < 4; ++dhb) {
                const int r = dhb * 16 + l15;
                const int sw = (r & 7) << 4;
                u16x4 v0 = *(const u16x4*)(Vb + r * 128 + ((ks * 64 + 8 * lhi) ^ sw));
                u16x4 v1 = *(const u16x4*)(Vb + r * 128 + ((ks * 64 + 32 + 8 * lhi) ^ sw));
                u16x8 vv = {v0[0], v0[1], v0[2], v0[3], v1[0], v1[1], v1[2], v1[3]};
                bf16x8 vf = __builtin_bit_cast(bf16x8, vv);
                o0[dhb] = MFMA16(vf, pb0, o0[dhb]);
                o1[dhb] = MFMA16(vf, pb1, o1[dhb]);
            }
            lac0 = MFMA16(onesA, pb0, lac0);   // row-sum on the matrix pipe
            lac1 = MFMA16(onesA, pb1, lac1);
        }
        __builtin_amdgcn_s_setprio(0);
    };

    stage(0, 0);
    int t = 0;
    for (;;) {
        __syncthreads();
        if (t + 1 < ntmax) stage(1, t + 1);
        if (t < ntW) computeChunk((const char*)Kl[0], (const char*)Vl[0], t);
        if (++t == ntmax) break;
        __syncthreads();
        if (t + 1 < ntmax) stage(0, t + 1);
        if (t < ntW) computeChunk((const char*)Kl[1], (const char*)Vl[1], t);
        if (++t == ntmax) break;
    }

    auto epi = [&](int qg0, const f32x4& lac, const f32x4* oa) {
        // non-row-0 slots of lac are exactly 0; sum slots + cross-lane = l
        float l = redsum_cross(lac[0] + lac[1] + lac[2] + lac[3]);
        const float rl = 1.f / l;
        const int q = qg0 + l15;
        const size_t rowoff = ((size_t)b * 2048 + q) * 1024 + h * 64;
#pragma unroll
        for (int dhb = 0; dhb < 4; ++dhb) {
            u16x4 w;
#pragma unroll
            for (int v = 0; v < 4; ++v) w[v] = f2bf(oa[dhb][v] * rl);
            *(u16x4*)&obuf[rowoff + dhb * 16 + lhi * 4] = w;
        }
    };
    epi(q0, lac0, o0);
    epi(q0 + 16, lac1, o1);
}

// ---------------------------------------------------------------------------
extern "C" void kernel_launch(void* const* d_in, const int* in_sizes, int n_in,
                              void* d_out, int out_size, void* d_ws, size_t ws_size,
                              hipStream_t stream) {
    const float* inp   = (const float*)d_in[0];   // [4,2048,1024]
    const float* W_qkv = (const float*)d_in[1];   // [1024,3072]
    const float* b_qkv = (const float*)d_in[2];   // [3072]
    const float* W_out = (const float*)d_in[3];   // [1024,1024]
    const float* b_out = (const float*)d_in[4];   // [1024]
    float* out = (float*)d_out;                   // [4,2048,1024] f32

    u16* xb   = (u16*)d_ws;          // 8192x1024
    u16* wqt  = xb + 8388608;        // 3072x1024
    u16* wot  = wqt + 3145728;       // 1024x1024
    u16* qbuf = wot + 1048576;       // [64][2048][64]
    u16* kbuf = qbuf + 8388608;
    u16* vtb  = kbuf + 8388608;      // [64][64][2048]  (written transposed by gemm)
    u16* obuf = vtb + 8388608;       // 8192x1024

    convert_f32_bf16<<<8192, 256, 0, stream>>>(inp, xb, 2097152);
    transpose_convert<<<dim3(16, 48), 256, 0, stream>>>(W_qkv, wqt, 1024, 3072);
    transpose_convert<<<dim3(16, 16), 256, 0, stream>>>(W_out, wot, 1024, 1024);
    gemm256_qkv<<<768, 512, 0, stream>>>(xb, wqt, b_qkv, qbuf, kbuf, vtb);
    attn_kernel<<<1024, 256, 0, stream>>>(qbuf, kbuf, vtb, obuf);
    gemm256_out<<<256, 512, 0, stream>>>(obuf, wot, b_out, out);
}

// Round 12
// 178.182 us; speedup vs baseline: 1.0467x; 1.0465x over previous
//
#include <hip/hip_runtime.h>
#include <hip/hip_bf16.h>

typedef unsigned short u16;
typedef unsigned u32;
typedef __attribute__((ext_vector_type(4))) unsigned short u16x4;
typedef __attribute__((ext_vector_type(8))) unsigned short u16x8;
typedef __attribute__((ext_vector_type(4))) unsigned u32x4;
typedef __attribute__((ext_vector_type(8))) __bf16 bf16x8;
typedef __attribute__((ext_vector_type(4))) float f32x4;

typedef __attribute__((address_space(1))) void as1v;
typedef __attribute__((address_space(3))) void as3v;

#define MFMA16(a, b, c) __builtin_amdgcn_mfma_f32_16x16x32_bf16(a, b, c, 0, 0, 0)

#if __has_builtin(__builtin_amdgcn_permlane16_swap) && __has_builtin(__builtin_amdgcn_permlane32_swap)
#define HAVE_PERMLANE_SWAP 1
#else
#define HAVE_PERMLANE_SWAP 0
#endif

__device__ __forceinline__ u16 f2bf(float f) {
    unsigned u = __builtin_bit_cast(unsigned, f);
    u += 0x7fffu + ((u >> 16) & 1u);
    return (u16)(u >> 16);
}

__device__ __forceinline__ u32 pkbf(float lo, float hi) {
    u32 r;
    asm("v_cvt_pk_bf16_f32 %0, %1, %2" : "=v"(r) : "v"(lo), "v"(hi));
    return r;
}

__device__ __forceinline__ void gload16(const void* g, void* l) {
    __builtin_amdgcn_global_load_lds((as1v*)g, (as3v*)l, 16, 0, 0);
}

// cross-lane reduce over lanes {l, l^16, l^32, l^48} — direction-proof.
__device__ __forceinline__ float redmax_cross(float v) {
#if HAVE_PERMLANE_SWAP
    u32 xu = __builtin_bit_cast(u32, v);
    auto r16 = __builtin_amdgcn_permlane16_swap(xu, xu, false, false);
    float a = fmaxf(__builtin_bit_cast(float, (u32)r16[0]),
                    __builtin_bit_cast(float, (u32)r16[1]));
    u32 au = __builtin_bit_cast(u32, a);
    auto r32 = __builtin_amdgcn_permlane32_swap(au, au, false, false);
    return fmaxf(__builtin_bit_cast(float, (u32)r32[0]),
                 __builtin_bit_cast(float, (u32)r32[1]));
#else
    v = fmaxf(v, __shfl_xor(v, 16, 64));
    return fmaxf(v, __shfl_xor(v, 32, 64));
#endif
}

__device__ __forceinline__ float redsum_cross(float v) {
#if HAVE_PERMLANE_SWAP
    u32 xu = __builtin_bit_cast(u32, v);
    auto r16 = __builtin_amdgcn_permlane16_swap(xu, xu, false, false);
    float a = __builtin_bit_cast(float, (u32)r16[0]) +
              __builtin_bit_cast(float, (u32)r16[1]);
    u32 au = __builtin_bit_cast(u32, a);
    auto r32 = __builtin_amdgcn_permlane32_swap(au, au, false, false);
    return __builtin_bit_cast(float, (u32)r32[0]) +
           __builtin_bit_cast(float, (u32)r32[1]);
#else
    v += __shfl_xor(v, 16, 64);
    return v + __shfl_xor(v, 32, 64);
#endif
}

// ---------------------------------------------------------------------------
__global__ void convert_f32_bf16(const float* __restrict__ in, u16* __restrict__ out, int n4) {
    int i = blockIdx.x * blockDim.x + threadIdx.x;
    if (i < n4) {
        float4 v = *(const float4*)&in[(size_t)i * 4];
        u16x4 o;
        o.x = f2bf(v.x); o.y = f2bf(v.y); o.z = f2bf(v.z); o.w = f2bf(v.w);
        *(u16x4*)&out[(size_t)i * 4] = o;
    }
}

// ---------------------------------------------------------------------------
__global__ void transpose_convert(const float* __restrict__ in, u16* __restrict__ out, int R, int C) {
    __shared__ float tl[64][65];
    const int rb = blockIdx.x, cb = blockIdx.y;
    const int tid = threadIdx.x;
    for (int it = 0; it < 4; ++it) {
        int lin = (tid + it * 256) * 4;
        int r = lin >> 6, c = lin & 63;
        float4 v = *(const float4*)&in[(size_t)(rb * 64 + r) * C + cb * 64 + c];
        tl[r][c + 0] = v.x; tl[r][c + 1] = v.y; tl[r][c + 2] = v.z; tl[r][c + 3] = v.w;
    }
    __syncthreads();
    for (int it = 0; it < 4; ++it) {
        int lin = (tid + it * 256) * 4;
        int oc = lin >> 6, orr = lin & 63;
        u16x4 o;
        o.x = f2bf(tl[orr + 0][oc]);
        o.y = f2bf(tl[orr + 1][oc]);
        o.z = f2bf(tl[orr + 2][oc]);
        o.w = f2bf(tl[orr + 3][oc]);
        *(u16x4*)&out[(size_t)(cb * 64 + oc) * R + rb * 64 + orr] = o;
    }
}

// ---------------------------------------------------------------------------
// QKV projection GEMM — many-small-blocks (m97 geometry + counted vmcnt).
// M=8192, N=3072, K=1024. 128x128 tile, 4 waves (2x2), wave tile 64x64, BK=32.
// LDS: 3-deep circular x (A 8KB + B 8KB) = 48 KB -> 3 blocks/CU (12 waves/CU;
// cross-block overlap hides barrier/vmcnt stalls — the m97 mechanism).
// Pipeline: compute t, stage t+2 into buf (t+2)%3 = (t-1)%3 (read-complete one
// barrier ago -> race-free). Steady s_waitcnt vmcnt(4). Grid 1536 = exactly
// 2 dispatch rounds at 3 blocks/CU, zero tail. XCD swizzle: 8 bm rows per XCD.
// Epilogue: Q/K direct scatter (r5-verified); V direct transposed (r11-verified).
__global__ __launch_bounds__(256, 3) void gemm128_qkv(
    const u16* __restrict__ A, const u16* __restrict__ Bt, const float* __restrict__ bias,
    u16* __restrict__ qb, u16* __restrict__ kb, u16* __restrict__ vtb) {
    constexpr int K = 1024;
    constexpr int NT = 32;
    __shared__ u16 ldsu[24576];   // 48 KB = 3 x (4096 A-elems + 4096 B-elems)

    const int bid = blockIdx.x;
    const int s = (bid & 7) * 192 + (bid >> 3);   // XCD-contiguous: 8 bm rows/XCD
    const int bm = s / 24, bn = s % 24;

    const int tid = threadIdx.x, wid = tid >> 6, lane = tid & 63;
    const int wr = wid >> 1, wc = wid & 1;
    const int l15 = lane & 15, lhi = lane >> 4;

    // staging source mapping (r9-verified algebra; 16-row x 1KB segments)
    const int sslot = (lane & 7) ^ (lane >> 3);
    const int kcol = (sslot & 3) * 8;
    const int mloc = (lane >> 3) * 2 + (sslot >> 2);

    const u16* Arow[2];
    const u16* Brow[2];
#pragma unroll
    for (int li = 0; li < 2; ++li) {
        int sg = wid * 2 + li;                      // 8 segments each for A, B
        Arow[li] = A + (size_t)(bm * 128 + sg * 16 + mloc) * K + kcol;
        Brow[li] = Bt + (size_t)(bn * 128 + sg * 16 + mloc) * K + kcol;
    }

    auto stageA = [&](int buf, int t) {
#pragma unroll
        for (int li = 0; li < 2; ++li) {
            int sg = wid * 2 + li;
            gload16(Arow[li] + t * 32, (char*)ldsu + buf * 16384 + sg * 1024);
        }
    };
    auto stageB = [&](int buf, int t) {
#pragma unroll
        for (int li = 0; li < 2; ++li) {
            int sg = wid * 2 + li;
            gload16(Brow[li] + t * 32, (char*)ldsu + buf * 16384 + 8192 + sg * 1024);
        }
    };

    const int rslot = ((l15 & 1) * 4 + lhi) ^ ((l15 >> 1) & 7);
    const int fragoff = (l15 >> 1) * 64 + rslot * 8;

    f32x4 acc[4][4];
#pragma unroll
    for (int i = 0; i < 4; ++i)
#pragma unroll
        for (int j = 0; j < 4; ++j) acc[i][j] = (f32x4){0.f, 0.f, 0.f, 0.f};

    auto doTile = [&](int cur, int tstage, bool dostage) {
        const u16* Ab = ldsu + cur * 8192 + wr * 2048 + fragoff;
        const u16* Bb = ldsu + cur * 8192 + 4096 + wc * 2048 + fragoff;
        bf16x8 af[4], b0, b1;
#pragma unroll
        for (int mf = 0; mf < 4; ++mf) af[mf] = *(const bf16x8*)(Ab + mf * 512);
        b0 = *(const bf16x8*)(Bb);
        b1 = *(const bf16x8*)(Bb + 512);
        if (dostage) stageA((tstage * 43691) >> 17 /*dummy*/ == -1 ? 0 : tstage % 3, tstage);
        __builtin_amdgcn_s_setprio(1);
#pragma unroll
        for (int mf = 0; mf < 4; ++mf) {
            acc[mf][0] = MFMA16(af[mf], b0, acc[mf][0]);
            acc[mf][1] = MFMA16(af[mf], b1, acc[mf][1]);
        }
        __builtin_amdgcn_s_setprio(0);
        b0 = *(const bf16x8*)(Bb + 1024);
        b1 = *(const bf16x8*)(Bb + 1536);
        if (dostage) stageB(tstage % 3, tstage);
        __builtin_amdgcn_s_setprio(1);
#pragma unroll
        for (int mf = 0; mf < 4; ++mf) {
            acc[mf][2] = MFMA16(af[mf], b0, acc[mf][2]);
            acc[mf][3] = MFMA16(af[mf], b1, acc[mf][3]);
        }
        __builtin_amdgcn_s_setprio(0);
    };

    // prologue: stage tiles 0 (buf0) and 1 (buf1)
    stageA(0, 0); stageB(0, 0);
    stageA(1, 1); stageB(1, 1);
    asm volatile("s_waitcnt vmcnt(4)" ::: "memory");   // tile 0 resident
    __builtin_amdgcn_s_barrier();
    __builtin_amdgcn_sched_barrier(0);

    for (int t = 0; t < NT - 2; ++t) {
        doTile(t % 3, t + 2, true);                    // stage t+2 into (t+2)%3
        asm volatile("s_waitcnt vmcnt(4)" ::: "memory"); // t+1 resident
        __builtin_amdgcn_s_barrier();
        __builtin_amdgcn_sched_barrier(0);
    }
    doTile((NT - 2) % 3, 0, false);
    asm volatile("s_waitcnt vmcnt(0)" ::: "memory");   // tile NT-1 resident
    __builtin_amdgcn_s_barrier();
    __builtin_amdgcn_sched_barrier(0);
    doTile((NT - 1) % 3, 0, false);

    // ---- epilogue: direct scatter (Q/K: [b,h][n][64]; V: transposed [b,h][dh][n])
    const int cg0 = bn * 128 + wc * 64;     // wave's 64-col group (uniform which)
    const int which = cg0 >> 10, rem = cg0 & 1023;
    const int hh = rem >> 6, dh0 = rem & 63;
    const int rgb0 = bm * 128 + wr * 64;
    const int bb = rgb0 >> 11, n0 = rgb0 & 2047;

    if (which == 2) {
        // V: transposed u16x4 stores along n (r11-verified pattern)
        const size_t vbase = ((size_t)(bb * 16 + hh) * 64 + dh0) * 2048 + (size_t)n0;
#pragma unroll
        for (int nt = 0; nt < 4; ++nt) {
            float bv = bias[cg0 + nt * 16 + l15];
            size_t rowb = vbase + (size_t)(nt * 16 + l15) * 2048;
#pragma unroll
            for (int mt = 0; mt < 4; ++mt) {
                u16x4 w;
#pragma unroll
                for (int v = 0; v < 4; ++v) w[v] = f2bf(acc[mt][nt][v] + bv);
                *(u16x4*)&vtb[rowb + mt * 16 + lhi * 4] = w;
            }
        }
    } else {
        u16* dst = (which == 0) ? qb : kb;
        const float qs = (which == 0) ? 0.18033688011112042f : 1.0f;  // 0.125*log2e
        const size_t gbase = (((size_t)bb * 16 + hh) * 2048 + n0) * 64 + dh0;
#pragma unroll
        for (int nt = 0; nt < 4; ++nt) {
            float bv = bias[cg0 + nt * 16 + l15];
#pragma unroll
            for (int mt = 0; mt < 4; ++mt)
#pragma unroll
                for (int v = 0; v < 4; ++v) {
                    int n = mt * 16 + lhi * 4 + v;
                    dst[gbase + (size_t)n * 64 + nt * 16 + l15] =
                        f2bf((acc[mt][nt][v] + bv) * qs);
                }
        }
    }
}

// ---------------------------------------------------------------------------
// Output projection GEMM, deep-pipelined 256x128 tile (verified r9-r11).
__global__ __launch_bounds__(512, 2) void gemm256_out(
    const u16* __restrict__ A, const u16* __restrict__ Bt, const float* __restrict__ bias,
    float* __restrict__ outf) {
    constexpr int K = 1024;
    constexpr int NT = 32;
    __shared__ u16 ldsu[49152];   // 96 KB

    const int bid = blockIdx.x;
    const int swz = (bid & 7) * 32 + (bid >> 3);   // XCD-contiguous bm
    const int bm = swz >> 3, bn = swz & 7;

    const int tid = threadIdx.x, wid = tid >> 6, lane = tid & 63;
    const int wr = wid >> 2, wc = wid & 3;
    const int l15 = lane & 15, lhi = lane >> 4;

    const int sslot = (lane & 7) ^ (lane >> 3);
    const int kcol = (sslot & 3) * 8;
    const int mloc = (lane >> 3) * 2 + (sslot >> 2);

    const u16* Arow[2];
#pragma unroll
    for (int li = 0; li < 2; ++li) {
        int sg = wid * 2 + li;
        Arow[li] = A + (size_t)(bm * 256 + sg * 16 + mloc) * K + kcol;
    }
    const u16* Brow = Bt + (size_t)(bn * 128 + wid * 16 + mloc) * K + kcol;

    auto stageA = [&](int buf, int t) {
#pragma unroll
        for (int li = 0; li < 2; ++li) {
            int sg = wid * 2 + li;
            gload16(Arow[li] + t * 32, (char*)ldsu + buf * 24576 + sg * 1024);
        }
    };
    auto stageB = [&](int buf, int t) {
        gload16(Brow + t * 32, (char*)ldsu + buf * 24576 + 16384 + wid * 1024);
    };

    const int rslot = ((l15 & 1) * 4 + lhi) ^ ((l15 >> 1) & 7);
    const int fragoff = (l15 >> 1) * 64 + rslot * 8;

    f32x4 acc[8][2];
#pragma unroll
    for (int i = 0; i < 8; ++i) {
        acc[i][0] = (f32x4){0.f, 0.f, 0.f, 0.f};
        acc[i][1] = (f32x4){0.f, 0.f, 0.f, 0.f};
    }

    auto doTile = [&](int cur, int tstage, bool dostage) {
        const u16* Ab = ldsu + cur * 12288 + wr * 4096 + fragoff;
        const u16* Bb = ldsu + cur * 12288 + 8192 + wc * 1024 + fragoff;
        bf16x8 af[8], b0, b1;
#pragma unroll
        for (int mf = 0; mf < 8; ++mf) af[mf] = *(const bf16x8*)(Ab + mf * 512);
        b0 = *(const bf16x8*)(Bb);
        b1 = *(const bf16x8*)(Bb + 512);
        if (dostage) stageA(tstage & 3, tstage);
        __builtin_amdgcn_s_setprio(1);
#pragma unroll
        for (int mf = 0; mf < 8; ++mf) acc[mf][0] = MFMA16(af[mf], b0, acc[mf][0]);
        __builtin_amdgcn_s_setprio(0);
        if (dostage) stageB(tstage & 3, tstage);
        __builtin_amdgcn_s_setprio(1);
#pragma unroll
        for (int mf = 0; mf < 8; ++mf) acc[mf][1] = MFMA16(af[mf], b1, acc[mf][1]);
        __builtin_amdgcn_s_setprio(0);
    };

    stageA(0, 0); stageB(0, 0);
    stageA(1, 1); stageB(1, 1);
    stageA(2, 2); stageB(2, 2);
    asm volatile("s_waitcnt vmcnt(6)" ::: "memory");
    __builtin_amdgcn_s_barrier();
    __builtin_amdgcn_sched_barrier(0);

    for (int t = 0; t < NT - 3; ++t) {
        doTile(t & 3, t + 3, true);
        asm volatile("s_waitcnt vmcnt(6)" ::: "memory");
        __builtin_amdgcn_s_barrier();
        __builtin_amdgcn_sched_barrier(0);
    }
    doTile((NT - 3) & 3, 0, false);
    asm volatile("s_waitcnt vmcnt(3)" ::: "memory");
    __builtin_amdgcn_s_barrier();
    __builtin_amdgcn_sched_barrier(0);
    doTile((NT - 2) & 3, 0, false);
    asm volatile("s_waitcnt vmcnt(0)" ::: "memory");
    __builtin_amdgcn_s_barrier();
    __builtin_amdgcn_sched_barrier(0);
    doTile((NT - 1) & 3, 0, false);

#pragma unroll
    for (int nf = 0; nf < 2; ++nf) {
        int cg = bn * 128 + wc * 32 + nf * 16 + l15;
        float bv = bias[cg];
#pragma unroll
        for (int mf = 0; mf < 8; ++mf) {
            int rgb = bm * 256 + wr * 128 + mf * 16 + lhi * 4;
#pragma unroll
            for (int v = 0; v < 4; ++v)
                outf[(size_t)(rgb + v) * 1024 + cg] = acc[mf][nf][v] + bv;
        }
    }
}

// ---------------------------------------------------------------------------
// Flash attention fwd, causal — 16x16x32 swapped-operand (r10 exact: best attn).
__global__ __launch_bounds__(256, 4) void attn_kernel(
    const u16* __restrict__ qbuf, const u16* __restrict__ kbuf,
    const u16* __restrict__ vtb, u16* __restrict__ obuf) {
    __shared__ u16 Kl[2][64 * 64];
    __shared__ u16 Vl[2][64 * 64];
    const int bid = blockIdx.x;
    const int rr = bid >> 8;
    const int pp = (bid >> 6) & 3;
    const int c = (rr & 1) ? (((rr >> 1) << 2) + pp)
                           : (15 - ((rr >> 1) << 2) - pp);
    const int bh = ((bid & 7) << 3) + ((bid >> 3) & 7);
    const int b = bh >> 4, h = bh & 15;
    const int tid = threadIdx.x, wid = tid >> 6, lane = tid & 63;
    const int l15 = lane & 15, lhi = lane >> 4;
    const int q0 = c * 128 + wid * 32;
    const int ntW = 2 * c + (wid >> 1) + 1;
    const int ntmax = 2 * c + 2;

    auto loadQ = [&](int qbase, bf16x8* dst) {
        const u16* qp = qbuf + ((size_t)bh * 2048 + qbase + l15) * 64 + lhi * 8;
        dst[0] = *(const bf16x8*)(qp);
        dst[1] = *(const bf16x8*)(qp + 32);
    };
    bf16x8 qf0[2], qf1[2];
    loadQ(q0, qf0); loadQ(q0 + 16, qf1);

    float m0 = -1e30f, l0 = 0.f, m1 = -1e30f, l1 = 0.f;
    f32x4 o0[4], o1[4];
#pragma unroll
    for (int d = 0; d < 4; ++d) {
        o0[d] = (f32x4){0.f, 0.f, 0.f, 0.f};
        o1[d] = (f32x4){0.f, 0.f, 0.f, 0.f};
    }

    const int srow = lane >> 3;
    const int scolb = ((lane & 7) * 16) ^ (srow << 4);

    auto stage = [&](int buf, int t) {
        const int kbase = t * 64;
#pragma unroll
        for (int s = 0; s < 2; ++s) {
            int sg = wid * 2 + s;
            int row = sg * 8 + srow;
            const u16* gk = kbuf + ((size_t)bh * 2048 + kbase + row) * 64 + (scolb >> 1);
            gload16(gk, (char*)Kl[buf] + sg * 1024);
            const u16* gv = vtb + ((size_t)bh * 64 + row) * 2048 + kbase + (scolb >> 1);
            gload16(gv, (char*)Vl[buf] + sg * 1024);
        }
    };

    auto smax = [&](f32x4* s, int qg0, int t, float& m, float& l, f32x4* oa, u32* pw) {
        const int qg = qg0 + l15;
        if (64 * t + 63 > qg0) {
#pragma unroll
            for (int kb4 = 0; kb4 < 4; ++kb4)
#pragma unroll
                for (int v = 0; v < 4; ++v) {
                    int kg = 64 * t + kb4 * 16 + lhi * 4 + v;
                    if (kg > qg) s[kb4][v] = -1e30f;
                }
        }
        float pm = fmaxf(fmaxf(fmaxf(s[0][0], s[0][1]), fmaxf(s[0][2], s[0][3])),
                         fmaxf(fmaxf(s[1][0], s[1][1]), fmaxf(s[1][2], s[1][3])));
        pm = fmaxf(pm, fmaxf(fmaxf(fmaxf(s[2][0], s[2][1]), fmaxf(s[2][2], s[2][3])),
                             fmaxf(fmaxf(s[3][0], s[3][1]), fmaxf(s[3][2], s[3][3]))));
        pm = redmax_cross(pm);
        if (!__all(pm <= m + 8.f)) {
            float nm = fmaxf(m, pm);
            float f = exp2f(m - nm);
            m = nm;
            l *= f;
#pragma unroll
            for (int d = 0; d < 4; ++d)
#pragma unroll
                for (int v = 0; v < 4; ++v) oa[d][v] *= f;
        }
        float rs = 0.f;
#pragma unroll
        for (int kb4 = 0; kb4 < 4; ++kb4)
#pragma unroll
            for (int v = 0; v < 4; ++v) {
                float e = exp2f(s[kb4][v] - m);
                s[kb4][v] = e;
                rs += e;
            }
        l += redsum_cross(rs);
        pw[0] = pkbf(s[0][0], s[0][1]); pw[1] = pkbf(s[0][2], s[0][3]);
        pw[2] = pkbf(s[1][0], s[1][1]); pw[3] = pkbf(s[1][2], s[1][3]);
        pw[4] = pkbf(s[2][0], s[2][1]); pw[5] = pkbf(s[2][2], s[2][3]);
        pw[6] = pkbf(s[3][0], s[3][1]); pw[7] = pkbf(s[3][2], s[3][3]);
    };

    auto computeChunk = [&](const char* Kb, const char* Vb, int t) {
        f32x4 s0[4], s1[4];
        __builtin_amdgcn_s_setprio(1);
#pragma unroll
        for (int kb4 = 0; kb4 < 4; ++kb4) {
            const int r = kb4 * 16 + l15;
            const int sw = (r & 7) << 4;
            const int rowb = r * 128;
            bf16x8 kf0 = *(const bf16x8*)(Kb + rowb + ((lhi * 16) ^ sw));
            bf16x8 kf1 = *(const bf16x8*)(Kb + rowb + ((64 + lhi * 16) ^ sw));
            f32x4 a0 = (f32x4){0.f, 0.f, 0.f, 0.f};
            a0 = MFMA16(kf0, qf0[0], a0);
            a0 = MFMA16(kf1, qf0[1], a0);
            s0[kb4] = a0;
            f32x4 a1 = (f32x4){0.f, 0.f, 0.f, 0.f};
            a1 = MFMA16(kf0, qf1[0], a1);
            a1 = MFMA16(kf1, qf1[1], a1);
            s1[kb4] = a1;
        }
        __builtin_amdgcn_s_setprio(0);
        u32 pw0[8], pw1[8];
        smax(s0, q0, t, m0, l0, o0, pw0);
        smax(s1, q0 + 16, t, m1, l1, o1, pw1);
        __builtin_amdgcn_s_setprio(1);
#pragma unroll
        for (int ks = 0; ks < 2; ++ks) {
            bf16x8 pb0 = __builtin_bit_cast(bf16x8,
                (u32x4){pw0[ks * 4 + 0], pw0[ks * 4 + 1], pw0[ks * 4 + 2], pw0[ks * 4 + 3]});
            bf16x8 pb1 = __builtin_bit_cast(bf16x8,
                (u32x4){pw1[ks * 4 + 0], pw1[ks * 4 + 1], pw1[ks * 4 + 2], pw1[ks * 4 + 3]});
#pragma unroll
            for (int dhb = 0; dhb < 4; ++dhb) {
                const int r = dhb * 16 + l15;
                const int sw = (r & 7) << 4;
                u16x4 v0 = *(const u16x4*)(Vb + r * 128 + ((ks * 64 + 8 * lhi) ^ sw));
                u16x4 v1 = *(const u16x4*)(Vb + r * 128 + ((ks * 64 + 32 + 8 * lhi) ^ sw));
                u16x8 vv = {v0[0], v0[1], v0[2], v0[3], v1[0], v1[1], v1[2], v1[3]};
                bf16x8 vf = __builtin_bit_cast(bf16x8, vv);
                o0[dhb] = MFMA16(vf, pb0, o0[dhb]);
                o1[dhb] = MFMA16(vf, pb1, o1[dhb]);
            }
        }
        __builtin_amdgcn_s_setprio(0);
    };

    stage(0, 0);
    int t = 0;
    for (;;) {
        __syncthreads();
        if (t + 1 < ntmax) stage(1, t + 1);
        if (t < ntW) computeChunk((const char*)Kl[0], (const char*)Vl[0], t);
        if (++t == ntmax) break;
        __syncthreads();
        if (t + 1 < ntmax) stage(0, t + 1);
        if (t < ntW) computeChunk((const char*)Kl[1], (const char*)Vl[1], t);
        if (++t == ntmax) break;
    }

    auto epi = [&](int qg0, float l, const f32x4* oa) {
        const float rl = 1.f / l;
        const int q = qg0 + l15;
        const size_t rowoff = ((size_t)b * 2048 + q) * 1024 + h * 64;
#pragma unroll
        for (int dhb = 0; dhb < 4; ++dhb) {
            u16x4 w;
#pragma unroll
            for (int v = 0; v < 4; ++v) w[v] = f2bf(oa[dhb][v] * rl);
            *(u16x4*)&obuf[rowoff + dhb * 16 + lhi * 4] = w;
        }
    };
    epi(q0, l0, o0);
    epi(q0 + 16, l1, o1);
}

// ---------------------------------------------------------------------------
extern "C" void kernel_launch(void* const* d_in, const int* in_sizes, int n_in,
                              void* d_out, int out_size, void* d_ws, size_t ws_size,
                              hipStream_t stream) {
    const float* inp   = (const float*)d_in[0];   // [4,2048,1024]
    const float* W_qkv = (const float*)d_in[1];   // [1024,3072]
    const float* b_qkv = (const float*)d_in[2];   // [3072]
    const float* W_out = (const float*)d_in[3];   // [1024,1024]
    const float* b_out = (const float*)d_in[4];   // [1024]
    float* out = (float*)d_out;                   // [4,2048,1024] f32

    u16* xb   = (u16*)d_ws;          // 8192x1024
    u16* wqt  = xb + 8388608;        // 3072x1024
    u16* wot  = wqt + 3145728;       // 1024x1024
    u16* qbuf = wot + 1048576;       // [64][2048][64]
    u16* kbuf = qbuf + 8388608;
    u16* vtb  = kbuf + 8388608;      // [64][64][2048]  (written transposed)
    u16* obuf = vtb + 8388608;       // 8192x1024

    convert_f32_bf16<<<8192, 256, 0, stream>>>(inp, xb, 2097152);
    transpose_convert<<<dim3(16, 48), 256, 0, stream>>>(W_qkv, wqt, 1024, 3072);
    transpose_convert<<<dim3(16, 16), 256, 0, stream>>>(W_out, wot, 1024, 1024);
    gemm128_qkv<<<1536, 256, 0, stream>>>(xb, wqt, b_qkv, qbuf, kbuf, vtb);
    attn_kernel<<<1024, 256, 0, stream>>>(qbuf, kbuf, vtb, obuf);
    gemm256_out<<<256, 512, 0, stream>>>(obuf, wot, b_out, out);
}